// Round 15
// baseline (112.344 us; speedup 1.0000x reference)
//
#include <hip/hip_runtime.h>

#define D 300
#define HDIM 512
#define ROWS 256          // X rows per block (grid 256)
#define WPB 128           // words per block
#define NKS 19            // k-extent 304 = 19*16 (300 data + bias@300 + pad)
#define NCH 13            // 5 M-chunks (64 cols each, 320 cols) + 8 V chunks
#define CH_STRIDE 40960   // chunk stride bytes (38912 used + pad)
#define CH_SELEMS 20480   // chunk stride in ushorts
#define REGB 19456        // 32-col region bytes (304 k * 32 * 2)
#define SEGW 5            // 1KB staging segments per wave per chunk (40/8)

typedef __attribute__((ext_vector_type(16))) float f32x16;
typedef __attribute__((ext_vector_type(4))) float f32x4;
typedef __attribute__((ext_vector_type(8))) short bf16x8;

__device__ inline unsigned short f2bf(float f) {
  unsigned int u = __float_as_uint(f);
  unsigned int r = (u + 0x7fffu + ((u >> 16) & 1u)) >> 16;
  return (unsigned short)r;
}

__device__ inline void gload_lds16(const void* g, void* l) {
  __builtin_amdgcn_global_load_lds(
      (const __attribute__((address_space(1))) unsigned int*)g,
      (__attribute__((address_space(3))) unsigned int*)l, 16, 0, 0);
}

// Chunks 0-4: Mt = W~q * W~k^T (301x301 kernel matrix, ones-feature folds both
// biases), cols padded to 320. Chunks 5-12: W~v (bias row at k=300).
// Region layout [ks19][kh2][col32][e8] (R10-verified conflict-free): element
// (reg,ks,kh,col,e) at ushort reg*9728 + ks*512 + kh*256 + col*8 + e.
__global__ __launch_bounds__(256) void prep_weights(
    const float* __restrict__ Wq, const float* __restrict__ Wk,
    const float* __restrict__ Wv, const float* __restrict__ bq,
    const float* __restrict__ bk, const float* __restrict__ bv,
    unsigned short* __restrict__ wt) {
  int idx = blockIdx.x * 256 + threadIdx.x;
  if (idx >= NCH * 19456) return;
  int c = idx / 19456, r = idx - c * 19456;
  int reg = r / 9728, r2 = r - reg * 9728;
  int ks = r2 >> 9, r3 = r2 & 511;
  int kh = r3 >> 8, r4 = r3 & 255;
  int col = r4 >> 3, e = r4 & 7;
  int k1 = ks * 16 + kh * 8 + e;
  int addr = c * CH_SELEMS + reg * 9728 + ks * 512 + kh * 256 + col * 8 + e;
  float v = 0.0f;
  if (c < 5) {
    int k2 = c * 64 + reg * 32 + col;
    if (k1 <= 300 && k2 <= 300) {
      const float* qrow = (k1 < 300) ? (Wq + k1 * HDIM) : bq;
      const float* krow = (k2 < 300) ? (Wk + k2 * HDIM) : bk;
      float acc = 0.f;
      for (int h = 0; h < HDIM; h += 4) {
        float4 q4 = *(const float4*)(qrow + h);
        float4 k4 = *(const float4*)(krow + h);
        acc += q4.x * k4.x + q4.y * k4.y + q4.z * k4.z + q4.w * k4.w;
      }
      v = acc;
    }
  } else {
    int gcol = (c - 5) * 64 + reg * 32 + col;
    if (k1 < D)       v = Wv[k1 * HDIM + gcol];
    else if (k1 == D) v = bv[gcol];
  }
  wt[addr] = f2bf(v);
}

// Scores via y = X~ * Mt then lane-local p += y * x~^T, where x~^T in C-layout
// comes from 2 identity-MFMAs (i0/i1 lane-constant B-frags). V phase = R14.
// NOTE: no 2nd __launch_bounds__ arg (R4-R6: halves VGPR pool -> spill).
__global__ __launch_bounds__(512) void fused_attn(
    const float* __restrict__ charv, const float* __restrict__ wordv,
    const unsigned short* __restrict__ wt, float* __restrict__ out) {
  extern __shared__ char lds[];
  float* sS  = (float*)(lds + 3 * CH_STRIDE);  // [128 w][4]; reused as sAt
  float* sAt = sS;

  const int tid  = threadIdx.x;
  const int wid  = tid >> 6;
  const int lane = tid & 63;
  const int lo5  = lane & 31;
  const int hi   = lane >> 5;

  auto stage = [&](int t) {
    const char* src = (const char*)wt + (long)t * CH_STRIDE + wid * (SEGW * 1024) + lane * 16;
    char* dst = lds + (t % 3) * CH_STRIDE + wid * (SEGW * 1024);
#pragma unroll
    for (int j = 0; j < SEGW; ++j)
      gload_lds16(src + j * 1024, dst + j * 1024);
  };

  stage(0);
  stage(1);

  // A-frag: lane holds x~[row=lo5][k=ks*16+hi*8+e]; ones-feature at k=300.
  bf16x8 a[NKS];
  {
    int row = blockIdx.x * ROWS + wid * 32 + lo5;
    const float* rp = ((row & 1) ? charv : wordv) + (row >> 1) * D;
#pragma unroll
    for (int ks = 0; ks < NKS; ++ks) {
      int k0 = ks * 16 + hi * 8;
      float4 lo = {0.f, 0.f, 0.f, 0.f}, hif = {0.f, 0.f, 0.f, 0.f};
      if (k0 + 8 <= D) {
        lo  = *(const float4*)(rp + k0);
        hif = *(const float4*)(rp + k0 + 4);
      } else if (k0 < D) {
        lo  = *(const float4*)(rp + k0);
      }
      bf16x8 v;
      v[0] = (short)f2bf(lo.x);  v[1] = (short)f2bf(lo.y);
      v[2] = (short)f2bf(lo.z);  v[3] = (short)f2bf(lo.w);
      v[4] = (short)f2bf(hif.x); v[5] = (short)f2bf(hif.y);
      v[6] = (short)f2bf(hif.z); v[7] = (short)f2bf(hif.w);
      if (ks == 18 && hi == 1) v[4] = (short)0x3F80;  // bf16(1.0) at k=300
      a[ks] = v;
    }
  }

  // Identity B-frags (lane-constant): i0 covers cols 0-15, i1 cols 16-31.
  bf16x8 i0, i1;
#pragma unroll
  for (int e = 0; e < 8; ++e) {
    i0[e] = (lo5 == hi * 8 + e)      ? (short)0x3F80 : (short)0;
    i1[e] = (lo5 == 16 + hi * 8 + e) ? (short)0x3F80 : (short)0;
  }

  float p[32];
#pragma unroll
  for (int t = 0; t < 32; ++t) p[t] = 0.f;

  const f32x16 zero16 = {0.f, 0.f, 0.f, 0.f, 0.f, 0.f, 0.f, 0.f,
                         0.f, 0.f, 0.f, 0.f, 0.f, 0.f, 0.f, 0.f};

  // ---- Phase A: 5 Mt chunks (fully unrolled: a[ks0] must be static, rule #20)
#pragma unroll
  for (int t = 0; t < 5; ++t) {
    asm volatile("s_waitcnt vmcnt(5)" ::: "memory");
    asm volatile("s_waitcnt lgkmcnt(0)" ::: "memory");
    __builtin_amdgcn_s_barrier();
    stage(t + 2);
    const char* cb = lds + (t % 3) * CH_STRIDE;
#pragma unroll
    for (int r = 0; r < 2; ++r) {
      const char* base = cb + r * REGB + hi * 512 + lo5 * 16;
      f32x16 accY = zero16;
      __builtin_amdgcn_s_setprio(1);
#pragma unroll
      for (int ks = 0; ks < NKS; ++ks) {
        bf16x8 mb = *(const bf16x8*)(base + ks * 1024);
        accY = __builtin_amdgcn_mfma_f32_32x32x16_bf16(a[ks], mb, accY, 0, 0, 0);
      }
      // x~^T chunk via identity MFMAs: accX[r'] = x~[crow(r')][c0+lo5]
      const int ks0 = t * 4 + r * 2;
      f32x16 accX = __builtin_amdgcn_mfma_f32_32x32x16_bf16(a[ks0], i0, zero16, 0, 0, 0);
      if (ks0 + 1 < NKS)
        accX = __builtin_amdgcn_mfma_f32_32x32x16_bf16(a[ks0 + 1], i1, accX, 0, 0, 0);
      __builtin_amdgcn_s_setprio(0);
      // lane-local: regs (2tt,2tt+1) = rows of word wid*16+(tt>>1)*4+(tt&1)+hi*2
#pragma unroll
      for (int tt = 0; tt < 8; ++tt)
#pragma unroll
        for (int i = 0; i < 2; ++i)
#pragma unroll
          for (int j = 0; j < 2; ++j)
            p[tt * 4 + i * 2 + j] += accY[2 * tt + i] * accX[2 * tt + j];
    }
  }

  // ---- reduce over 32 col-lanes, softmax (stages 5,6 remain in flight)
#pragma unroll
  for (int t = 0; t < 32; ++t) {
    float v = p[t];
    v += __shfl_xor(v, 1);
    v += __shfl_xor(v, 2);
    v += __shfl_xor(v, 4);
    v += __shfl_xor(v, 8);
    v += __shfl_xor(v, 16);
    p[t] = v;
  }
  if (lo5 == 0) {
#pragma unroll
    for (int tt = 0; tt < 8; ++tt) {
      int w = wid * 16 + (tt >> 1) * 4 + (tt & 1) + hi * 2;
#pragma unroll
      for (int q = 0; q < 4; ++q) sS[w * 4 + q] = p[tt * 4 + q];
    }
  }
  asm volatile("s_waitcnt lgkmcnt(0)" ::: "memory");
  __builtin_amdgcn_s_barrier();
  if (tid < 128) {
    const float sc = 0.044194173824159216f;  // 1/sqrt(512)
    float s[4];
#pragma unroll
    for (int t = 0; t < 4; ++t) s[t] = sS[tid * 4 + t] * sc;
#pragma unroll
    for (int i = 0; i < 2; ++i) {
      float m  = fmaxf(s[i * 2], s[i * 2 + 1]);
      float e0 = expf(s[i * 2] - m), e1 = expf(s[i * 2 + 1] - m);
      float inv = 1.0f / (e0 + e1);
      sAt[tid * 4 + i * 2]     = e0 * inv;
      sAt[tid * 4 + i * 2 + 1] = e1 * inv;
    }
  }
  asm volatile("s_waitcnt lgkmcnt(0)" ::: "memory");
  __builtin_amdgcn_s_barrier();

  f32x4 at[8];
#pragma unroll
  for (int tt = 0; tt < 8; ++tt) {
    int w = wid * 16 + (tt >> 1) * 4 + (tt & 1) + hi * 2;
    at[tt] = *(const f32x4*)(sAt + w * 4);
  }

  // ---- Phase B: 8 V chunks; vmcnt(37) = 5 stage + 32 stores newer
  for (int t = 5; t < NCH; ++t) {
    if (t == 5) asm volatile("s_waitcnt vmcnt(5)" ::: "memory");
    else        asm volatile("s_waitcnt vmcnt(37)" ::: "memory");
    asm volatile("s_waitcnt lgkmcnt(0)" ::: "memory");
    __builtin_amdgcn_s_barrier();
    if (t + 2 < NCH) stage(t + 2);
    const char* base = lds + (t % 3) * CH_STRIDE + hi * 512 + lo5 * 16;
    const int g = t - 5;
#pragma unroll
    for (int ct = 0; ct < 2; ++ct) {
      f32x16 accV = zero16;
      __builtin_amdgcn_s_setprio(1);
#pragma unroll
      for (int ks = 0; ks < NKS; ++ks) {
        bf16x8 vb = *(const bf16x8*)(base + ct * REGB + ks * 1024);
        accV = __builtin_amdgcn_mfma_f32_32x32x16_bf16(a[ks], vb, accV, 0, 0, 0);
      }
      __builtin_amdgcn_s_setprio(0);
      int h = g * 64 + ct * 32 + lo5;
#pragma unroll
      for (int tt = 0; tt < 8; ++tt) {
        int w = wid * 16 + (tt >> 1) * 4 + (tt & 1) + hi * 2;
        long gw = (long)(blockIdx.x * WPB + w);
        float v0 = accV[2 * tt], v1 = accV[2 * tt + 1];
        out[gw * 1024 + h]       = at[tt][0] * v0 + at[tt][1] * v1;
        out[gw * 1024 + 512 + h] = at[tt][2] * v0 + at[tt][3] * v1;
      }
    }
  }
}

extern "C" void kernel_launch(void* const* d_in, const int* in_sizes, int n_in,
                              void* d_out, int out_size, void* d_ws, size_t ws_size,
                              hipStream_t stream) {
  const float* charv = (const float*)d_in[0];
  const float* wordv = (const float*)d_in[1];
  const float* Wk = (const float*)d_in[2];
  const float* bk = (const float*)d_in[3];
  const float* Wq = (const float*)d_in[4];
  const float* bq = (const float*)d_in[5];
  const float* Wv = (const float*)d_in[6];
  const float* bv = (const float*)d_in[7];
  float* out = (float*)d_out;
  unsigned short* wt = (unsigned short*)d_ws;  // 13*20480*2 = 532,480 B

  prep_weights<<<(NCH * 19456 + 255) / 256, 256, 0, stream>>>(
      Wq, Wk, Wv, bq, bk, bv, wt);

  const int lds_bytes = 3 * CH_STRIDE + 512 * 4;  // 124,928 B
  fused_attn<<<65536 / ROWS, 512, lds_bytes, stream>>>(charv, wordv, wt, out);
}

// Round 16
// 112.271 us; speedup vs baseline: 1.0006x; 1.0006x over previous
//
#include <hip/hip_runtime.h>

#define D 300
#define HDIM 512
#define ROWS 256          // X rows per block (grid 256)
#define WPB 128           // words per block
#define NKS 19            // k-extent 304 = 19*16 (300 data + bias@300 + pad)
#define NCH 13            // 5 M-chunks (64 cols each, 320 cols) + 8 V chunks
#define CH_STRIDE 40960   // chunk stride bytes (38912 used + pad)
#define CH_SELEMS 20480   // chunk stride in ushorts
#define REGB 19456        // 32-col region bytes (304 k * 32 * 2)
#define SEGW 5            // 1KB staging segments per wave per chunk (40/8)

typedef __attribute__((ext_vector_type(16))) float f32x16;
typedef __attribute__((ext_vector_type(4))) float f32x4;
typedef __attribute__((ext_vector_type(8))) short bf16x8;

__device__ inline unsigned short f2bf(float f) {
  unsigned int u = __float_as_uint(f);
  unsigned int r = (u + 0x7fffu + ((u >> 16) & 1u)) >> 16;
  return (unsigned short)r;
}

__device__ inline void gload_lds16(const void* g, void* l) {
  __builtin_amdgcn_global_load_lds(
      (const __attribute__((address_space(1))) unsigned int*)g,
      (__attribute__((address_space(3))) unsigned int*)l, 16, 0, 0);
}

// Chunks 0-4: Mt = W~q * W~k^T (301x301 kernel matrix, ones-feature folds both
// biases), cols padded to 320. Chunks 5-12: W~v (bias row at k=300).
// Region layout [ks19][kh2][col32][e8] (R10-verified conflict-free).
__global__ __launch_bounds__(256) void prep_weights(
    const float* __restrict__ Wq, const float* __restrict__ Wk,
    const float* __restrict__ Wv, const float* __restrict__ bq,
    const float* __restrict__ bk, const float* __restrict__ bv,
    unsigned short* __restrict__ wt) {
  int idx = blockIdx.x * 256 + threadIdx.x;
  if (idx >= NCH * 19456) return;
  int c = idx / 19456, r = idx - c * 19456;
  int reg = r / 9728, r2 = r - reg * 9728;
  int ks = r2 >> 9, r3 = r2 & 511;
  int kh = r3 >> 8, r4 = r3 & 255;
  int col = r4 >> 3, e = r4 & 7;
  int k1 = ks * 16 + kh * 8 + e;
  int addr = c * CH_SELEMS + reg * 9728 + ks * 512 + kh * 256 + col * 8 + e;
  float v = 0.0f;
  if (c < 5) {
    int k2 = c * 64 + reg * 32 + col;
    if (k1 <= 300 && k2 <= 300) {
      const float* qrow = (k1 < 300) ? (Wq + k1 * HDIM) : bq;
      const float* krow = (k2 < 300) ? (Wk + k2 * HDIM) : bk;
      float acc = 0.f;
      for (int h = 0; h < HDIM; h += 4) {
        float4 q4 = *(const float4*)(qrow + h);
        float4 k4 = *(const float4*)(krow + h);
        acc += q4.x * k4.x + q4.y * k4.y + q4.z * k4.z + q4.w * k4.w;
      }
      v = acc;
    }
  } else {
    int gcol = (c - 5) * 64 + reg * 32 + col;
    if (k1 < D)       v = Wv[k1 * HDIM + gcol];
    else if (k1 == D) v = bv[gcol];
  }
  wt[addr] = f2bf(v);
}

// Scores via y = X~ * Mt then lane-local p += y * x~^T (x~^T from 2 identity
// MFMAs). LDS = 125 KB -> 1 block/CU ALWAYS, so VGPR caps above 256/8-waves
// buy nothing: __launch_bounds__(512,1) -> cap 256, kills R15's spill
// (VGPR=128 + 120 MB scratch traffic) at zero occupancy cost.
__global__ __launch_bounds__(512, 1) void fused_attn(
    const float* __restrict__ charv, const float* __restrict__ wordv,
    const unsigned short* __restrict__ wt, float* __restrict__ out) {
  extern __shared__ char lds[];
  float* sS  = (float*)(lds + 3 * CH_STRIDE);  // [128 w][4]; reused as sAt
  float* sAt = sS;

  const int tid  = threadIdx.x;
  const int wid  = tid >> 6;
  const int lane = tid & 63;
  const int lo5  = lane & 31;
  const int hi   = lane >> 5;

  auto stage = [&](int t) {
    const char* src = (const char*)wt + (long)t * CH_STRIDE + wid * (SEGW * 1024) + lane * 16;
    char* dst = lds + (t % 3) * CH_STRIDE + wid * (SEGW * 1024);
#pragma unroll
    for (int j = 0; j < SEGW; ++j)
      gload_lds16(src + j * 1024, dst + j * 1024);
  };

  stage(0);
  stage(1);

  // A-frag: lane holds x~[row=lo5][k=ks*16+hi*8+e]; ones-feature at k=300.
  bf16x8 a[NKS];
  {
    int row = blockIdx.x * ROWS + wid * 32 + lo5;
    const float* rp = ((row & 1) ? charv : wordv) + (row >> 1) * D;
#pragma unroll
    for (int ks = 0; ks < NKS; ++ks) {
      int k0 = ks * 16 + hi * 8;
      float4 lo = {0.f, 0.f, 0.f, 0.f}, hif = {0.f, 0.f, 0.f, 0.f};
      if (k0 + 8 <= D) {
        lo  = *(const float4*)(rp + k0);
        hif = *(const float4*)(rp + k0 + 4);
      } else if (k0 < D) {
        lo  = *(const float4*)(rp + k0);
      }
      bf16x8 v;
      v[0] = (short)f2bf(lo.x);  v[1] = (short)f2bf(lo.y);
      v[2] = (short)f2bf(lo.z);  v[3] = (short)f2bf(lo.w);
      v[4] = (short)f2bf(hif.x); v[5] = (short)f2bf(hif.y);
      v[6] = (short)f2bf(hif.z); v[7] = (short)f2bf(hif.w);
      if (ks == 18 && hi == 1) v[4] = (short)0x3F80;  // bf16(1.0) at k=300
      a[ks] = v;
    }
  }

  // Identity B-frags (lane-constant): i0 covers cols 0-15, i1 cols 16-31.
  bf16x8 i0, i1;
#pragma unroll
  for (int e = 0; e < 8; ++e) {
    i0[e] = (lo5 == hi * 8 + e)      ? (short)0x3F80 : (short)0;
    i1[e] = (lo5 == 16 + hi * 8 + e) ? (short)0x3F80 : (short)0;
  }

  float p[32];
#pragma unroll
  for (int t = 0; t < 32; ++t) p[t] = 0.f;

  const f32x16 zero16 = {0.f, 0.f, 0.f, 0.f, 0.f, 0.f, 0.f, 0.f,
                         0.f, 0.f, 0.f, 0.f, 0.f, 0.f, 0.f, 0.f};

  // ---- Phase A: 5 Mt chunks (fully unrolled: a[ks0] must be static, rule #20)
#pragma unroll
  for (int t = 0; t < 5; ++t) {
    asm volatile("s_waitcnt vmcnt(5)" ::: "memory");
    asm volatile("s_waitcnt lgkmcnt(0)" ::: "memory");
    __builtin_amdgcn_s_barrier();
    stage(t + 2);
    const char* cb = lds + (t % 3) * CH_STRIDE;
#pragma unroll
    for (int r = 0; r < 2; ++r) {
      const char* base = cb + r * REGB + hi * 512 + lo5 * 16;
      f32x16 accY = zero16;
      __builtin_amdgcn_s_setprio(1);
#pragma unroll
      for (int ks = 0; ks < NKS; ++ks) {
        bf16x8 mb = *(const bf16x8*)(base + ks * 1024);
        accY = __builtin_amdgcn_mfma_f32_32x32x16_bf16(a[ks], mb, accY, 0, 0, 0);
      }
      // x~^T chunk via identity MFMAs: accX[r'] = x~[crow(r')][c0+lo5]
      const int ks0 = t * 4 + r * 2;
      f32x16 accX = __builtin_amdgcn_mfma_f32_32x32x16_bf16(a[ks0], i0, zero16, 0, 0, 0);
      if (ks0 + 1 < NKS)
        accX = __builtin_amdgcn_mfma_f32_32x32x16_bf16(a[ks0 + 1], i1, accX, 0, 0, 0);
      __builtin_amdgcn_s_setprio(0);
      // lane-local: regs (2tt,2tt+1) = rows of word wid*16+(tt>>1)*4+(tt&1)+hi*2
#pragma unroll
      for (int tt = 0; tt < 8; ++tt)
#pragma unroll
        for (int i = 0; i < 2; ++i)
#pragma unroll
          for (int j = 0; j < 2; ++j)
            p[tt * 4 + i * 2 + j] += accY[2 * tt + i] * accX[2 * tt + j];
    }
  }

  // ---- reduce over 32 col-lanes, softmax (stages 5,6 remain in flight)
#pragma unroll
  for (int t = 0; t < 32; ++t) {
    float v = p[t];
    v += __shfl_xor(v, 1);
    v += __shfl_xor(v, 2);
    v += __shfl_xor(v, 4);
    v += __shfl_xor(v, 8);
    v += __shfl_xor(v, 16);
    p[t] = v;
  }
  if (lo5 == 0) {
#pragma unroll
    for (int tt = 0; tt < 8; ++tt) {
      int w = wid * 16 + (tt >> 1) * 4 + (tt & 1) + hi * 2;
#pragma unroll
      for (int q = 0; q < 4; ++q) sS[w * 4 + q] = p[tt * 4 + q];
    }
  }
  asm volatile("s_waitcnt lgkmcnt(0)" ::: "memory");
  __builtin_amdgcn_s_barrier();
  if (tid < 128) {
    const float sc = 0.044194173824159216f;  // 1/sqrt(512)
    float s[4];
#pragma unroll
    for (int t = 0; t < 4; ++t) s[t] = sS[tid * 4 + t] * sc;
#pragma unroll
    for (int i = 0; i < 2; ++i) {
      float m  = fmaxf(s[i * 2], s[i * 2 + 1]);
      float e0 = expf(s[i * 2] - m), e1 = expf(s[i * 2 + 1] - m);
      float inv = 1.0f / (e0 + e1);
      sAt[tid * 4 + i * 2]     = e0 * inv;
      sAt[tid * 4 + i * 2 + 1] = e1 * inv;
    }
  }
  asm volatile("s_waitcnt lgkmcnt(0)" ::: "memory");
  __builtin_amdgcn_s_barrier();

  f32x4 at[8];
#pragma unroll
  for (int tt = 0; tt < 8; ++tt) {
    int w = wid * 16 + (tt >> 1) * 4 + (tt & 1) + hi * 2;
    at[tt] = *(const f32x4*)(sAt + w * 4);
  }

  // ---- Phase B: 8 V chunks; vmcnt(37) = 5 stage + 32 stores newer
  for (int t = 5; t < NCH; ++t) {
    if (t == 5) asm volatile("s_waitcnt vmcnt(5)" ::: "memory");
    else        asm volatile("s_waitcnt vmcnt(37)" ::: "memory");
    asm volatile("s_waitcnt lgkmcnt(0)" ::: "memory");
    __builtin_amdgcn_s_barrier();
    if (t + 2 < NCH) stage(t + 2);
    const char* base = lds + (t % 3) * CH_STRIDE + hi * 512 + lo5 * 16;
    const int g = t - 5;
#pragma unroll
    for (int ct = 0; ct < 2; ++ct) {
      f32x16 accV = zero16;
      __builtin_amdgcn_s_setprio(1);
#pragma unroll
      for (int ks = 0; ks < NKS; ++ks) {
        bf16x8 vb = *(const bf16x8*)(base + ct * REGB + ks * 1024);
        accV = __builtin_amdgcn_mfma_f32_32x32x16_bf16(a[ks], vb, accV, 0, 0, 0);
      }
      __builtin_amdgcn_s_setprio(0);
      int h = g * 64 + ct * 32 + lo5;
#pragma unroll
      for (int tt = 0; tt < 8; ++tt) {
        int w = wid * 16 + (tt >> 1) * 4 + (tt & 1) + hi * 2;
        long gw = (long)(blockIdx.x * WPB + w);
        float v0 = accV[2 * tt], v1 = accV[2 * tt + 1];
        out[gw * 1024 + h]       = at[tt][0] * v0 + at[tt][1] * v1;
        out[gw * 1024 + 512 + h] = at[tt][2] * v0 + at[tt][3] * v1;
      }
    }
  }
}

extern "C" void kernel_launch(void* const* d_in, const int* in_sizes, int n_in,
                              void* d_out, int out_size, void* d_ws, size_t ws_size,
                              hipStream_t stream) {
  const float* charv = (const float*)d_in[0];
  const float* wordv = (const float*)d_in[1];
  const float* Wk = (const float*)d_in[2];
  const float* bk = (const float*)d_in[3];
  const float* Wq = (const float*)d_in[4];
  const float* bq = (const float*)d_in[5];
  const float* Wv = (const float*)d_in[6];
  const float* bv = (const float*)d_in[7];
  float* out = (float*)d_out;
  unsigned short* wt = (unsigned short*)d_ws;  // 13*20480*2 = 532,480 B

  prep_weights<<<(NCH * 19456 + 255) / 256, 256, 0, stream>>>(
      Wq, Wk, Wv, bq, bk, bv, wt);

  const int lds_bytes = 3 * CH_STRIDE + 512 * 4;  // 124,928 B
  fused_attn<<<65536 / ROWS, 512, lds_bytes, stream>>>(charv, wordv, wt, out);
}

// Round 17
// 106.198 us; speedup vs baseline: 1.0579x; 1.0572x over previous
//
#include <hip/hip_runtime.h>

#define D 300
#define HDIM 512
#define ROWS 128          // X rows per block (grid 512 = 2 blocks/CU)
#define WPB 64            // words per block
#define NKS 19            // k-extent 304 = 19*16 (300 data + bias@300 + pad)
#define NCHA 10           // Mt chunks (32 cols each, 320 cols)
#define NCH 26            // 10 Mt + 16 V chunks
#define CH_STRIDE 20480   // chunk stride bytes (19456 used + 1KB pad seg)
#define CH_SELEMS 10240   // chunk stride in ushorts
#define SEGW 5            // 1KB staging segments per wave per chunk (20/4)

typedef __attribute__((ext_vector_type(16))) float f32x16;
typedef __attribute__((ext_vector_type(4))) float f32x4;
typedef __attribute__((ext_vector_type(8))) short bf16x8;

__device__ inline unsigned short f2bf(float f) {
  unsigned int u = __float_as_uint(f);
  unsigned int r = (u + 0x7fffu + ((u >> 16) & 1u)) >> 16;
  return (unsigned short)r;
}

__device__ inline void gload_lds16(const void* g, void* l) {
  __builtin_amdgcn_global_load_lds(
      (const __attribute__((address_space(1))) unsigned int*)g,
      (__attribute__((address_space(3))) unsigned int*)l, 16, 0, 0);
}

// Chunks 0-9: Mt = W~q * W~k^T (301x301 kernel matrix, ones-feature folds both
// biases), cols 32t..32t+31, padded to 320. Chunks 10-25: W~v (bias@k=300).
// Chunk layout [ks19][kh2][col32][e8] (R10-verified conflict-free); last 1KB
// of each 20KB chunk is pad (staged but never read).
__global__ __launch_bounds__(256) void prep_weights(
    const float* __restrict__ Wq, const float* __restrict__ Wk,
    const float* __restrict__ Wv, const float* __restrict__ bq,
    const float* __restrict__ bk, const float* __restrict__ bv,
    unsigned short* __restrict__ wt) {
  int idx = blockIdx.x * 256 + threadIdx.x;
  if (idx >= NCH * 9728) return;
  int c = idx / 9728, r2 = idx - c * 9728;
  int ks = r2 >> 9, r3 = r2 & 511;
  int kh = r3 >> 8, r4 = r3 & 255;
  int col = r4 >> 3, e = r4 & 7;
  int k1 = ks * 16 + kh * 8 + e;
  int addr = c * CH_SELEMS + ks * 512 + kh * 256 + col * 8 + e;
  float v = 0.0f;
  if (c < NCHA) {
    int k2 = c * 32 + col;
    if (k1 <= 300 && k2 <= 300) {
      const float* qrow = (k1 < 300) ? (Wq + k1 * HDIM) : bq;
      const float* krow = (k2 < 300) ? (Wk + k2 * HDIM) : bk;
      float acc = 0.f;
      for (int h = 0; h < HDIM; h += 4) {
        float4 q4 = *(const float4*)(qrow + h);
        float4 k4 = *(const float4*)(krow + h);
        acc += q4.x * k4.x + q4.y * k4.y + q4.z * k4.z + q4.w * k4.w;
      }
      v = acc;
    }
  } else {
    int gcol = (c - NCHA) * 32 + col;
    if (k1 < D)       v = Wv[k1 * HDIM + gcol];
    else if (k1 == D) v = bv[gcol];
  }
  wt[addr] = f2bf(v);
}

// 256-thread blocks: R7-R16 measured that 512-thread blocks are VGPR-capped at
// 128 (R15's ~155-reg live set spilled 120 MB); 256-thread blocks allocate up
// to 256 (R8: 232, R13: 256). Algorithm = R15 (Mt kernel-matrix scores +
// identity-MFMA x~^T), skeleton = R10 (triple buffer, counted vmcnt).
__global__ __launch_bounds__(256) void fused_attn(
    const float* __restrict__ charv, const float* __restrict__ wordv,
    const unsigned short* __restrict__ wt, float* __restrict__ out) {
  extern __shared__ char lds[];
  float* sS  = (float*)(lds + 3 * CH_STRIDE);  // [64 w][4]; reused as sAt
  float* sAt = sS;

  const int tid  = threadIdx.x;
  const int wid  = tid >> 6;    // 0..3
  const int lane = tid & 63;
  const int lo5  = lane & 31;
  const int hi   = lane >> 5;

  auto stage = [&](int t) {
    const char* src = (const char*)wt + (long)t * CH_STRIDE + wid * (SEGW * 1024) + lane * 16;
    char* dst = lds + (t % 3) * CH_STRIDE + wid * (SEGW * 1024);
#pragma unroll
    for (int j = 0; j < SEGW; ++j)
      gload_lds16(src + j * 1024, dst + j * 1024);
  };

  stage(0);
  stage(1);

  // A-frag: lane holds x~[row=lo5][k=ks*16+hi*8+e]; ones-feature at k=300.
  bf16x8 a[NKS];
  {
    int row = blockIdx.x * ROWS + wid * 32 + lo5;
    const float* rp = ((row & 1) ? charv : wordv) + (row >> 1) * D;
#pragma unroll
    for (int ks = 0; ks < NKS; ++ks) {
      int k0 = ks * 16 + hi * 8;
      float4 lo = {0.f, 0.f, 0.f, 0.f}, hif = {0.f, 0.f, 0.f, 0.f};
      if (k0 + 8 <= D) {
        lo  = *(const float4*)(rp + k0);
        hif = *(const float4*)(rp + k0 + 4);
      } else if (k0 < D) {
        lo  = *(const float4*)(rp + k0);
      }
      bf16x8 v;
      v[0] = (short)f2bf(lo.x);  v[1] = (short)f2bf(lo.y);
      v[2] = (short)f2bf(lo.z);  v[3] = (short)f2bf(lo.w);
      v[4] = (short)f2bf(hif.x); v[5] = (short)f2bf(hif.y);
      v[6] = (short)f2bf(hif.z); v[7] = (short)f2bf(hif.w);
      if (ks == 18 && hi == 1) v[4] = (short)0x3F80;  // bf16(1.0) at k=300
      a[ks] = v;
    }
  }

  // Identity B-frags (lane-constant): i0 covers cols 0-15, i1 cols 16-31.
  bf16x8 i0, i1;
#pragma unroll
  for (int e = 0; e < 8; ++e) {
    i0[e] = (lo5 == hi * 8 + e)      ? (short)0x3F80 : (short)0;
    i1[e] = (lo5 == 16 + hi * 8 + e) ? (short)0x3F80 : (short)0;
  }

  float p[32];
#pragma unroll
  for (int t = 0; t < 32; ++t) p[t] = 0.f;

  const f32x16 zero16 = {0.f, 0.f, 0.f, 0.f, 0.f, 0.f, 0.f, 0.f,
                         0.f, 0.f, 0.f, 0.f, 0.f, 0.f, 0.f, 0.f};

  // ---- Phase A: 10 Mt chunks (unrolled: a[2t] must be static, rule #20)
#pragma unroll
  for (int t = 0; t < NCHA; ++t) {
    asm volatile("s_waitcnt vmcnt(5)" ::: "memory");   // stage(t) landed
    asm volatile("s_waitcnt lgkmcnt(0)" ::: "memory");
    __builtin_amdgcn_s_barrier();
    stage(t + 2);
    const char* base = lds + (t % 3) * CH_STRIDE + hi * 512 + lo5 * 16;
    f32x16 accY = zero16;
    __builtin_amdgcn_s_setprio(1);
#pragma unroll
    for (int ks = 0; ks < NKS; ++ks) {
      bf16x8 mb = *(const bf16x8*)(base + ks * 1024);
      accY = __builtin_amdgcn_mfma_f32_32x32x16_bf16(a[ks], mb, accY, 0, 0, 0);
    }
    // x~^T chunk via identity MFMAs: accX[r'] = x~[crow(r')][t*32+lo5]
    f32x16 accX = __builtin_amdgcn_mfma_f32_32x32x16_bf16(a[2 * t], i0, zero16, 0, 0, 0);
    accX = __builtin_amdgcn_mfma_f32_32x32x16_bf16(a[2 * t + 1], i1, accX, 0, 0, 0);
    __builtin_amdgcn_s_setprio(0);
    // lane-local: regs (2tt,2tt+1) = rows of word wid*16+(tt>>1)*4+(tt&1)+hi*2
#pragma unroll
    for (int tt = 0; tt < 8; ++tt)
#pragma unroll
      for (int i = 0; i < 2; ++i)
#pragma unroll
        for (int j = 0; j < 2; ++j)
          p[tt * 4 + i * 2 + j] += accY[2 * tt + i] * accX[2 * tt + j];
  }

  // ---- reduce over 32 col-lanes, softmax (stages 10,11 remain in flight)
#pragma unroll
  for (int t = 0; t < 32; ++t) {
    float v = p[t];
    v += __shfl_xor(v, 1);
    v += __shfl_xor(v, 2);
    v += __shfl_xor(v, 4);
    v += __shfl_xor(v, 8);
    v += __shfl_xor(v, 16);
    p[t] = v;
  }
  if (lo5 == 0) {
#pragma unroll
    for (int tt = 0; tt < 8; ++tt) {
      int w = wid * 16 + (tt >> 1) * 4 + (tt & 1) + hi * 2;
#pragma unroll
      for (int q = 0; q < 4; ++q) sS[w * 4 + q] = p[tt * 4 + q];
    }
  }
  asm volatile("s_waitcnt lgkmcnt(0)" ::: "memory");
  __builtin_amdgcn_s_barrier();
  if (tid < 64) {
    const float sc = 0.044194173824159216f;  // 1/sqrt(512)
    float s[4];
#pragma unroll
    for (int t = 0; t < 4; ++t) s[t] = sS[tid * 4 + t] * sc;
#pragma unroll
    for (int i = 0; i < 2; ++i) {
      float m  = fmaxf(s[i * 2], s[i * 2 + 1]);
      float e0 = expf(s[i * 2] - m), e1 = expf(s[i * 2 + 1] - m);
      float inv = 1.0f / (e0 + e1);
      sAt[tid * 4 + i * 2]     = e0 * inv;
      sAt[tid * 4 + i * 2 + 1] = e1 * inv;
    }
  }
  asm volatile("s_waitcnt lgkmcnt(0)" ::: "memory");
  __builtin_amdgcn_s_barrier();

  f32x4 at[8];
#pragma unroll
  for (int tt = 0; tt < 8; ++tt) {
    int w = wid * 16 + (tt >> 1) * 4 + (tt & 1) + hi * 2;
    at[tt] = *(const f32x4*)(sAt + w * 4);
  }

  // ---- Phase B: 16 V chunks; vmcnt(21) = 5 stage + 16 stores newer
  for (int t = NCHA; t < NCH; ++t) {
    if (t == NCHA) asm volatile("s_waitcnt vmcnt(5)" ::: "memory");
    else           asm volatile("s_waitcnt vmcnt(21)" ::: "memory");
    asm volatile("s_waitcnt lgkmcnt(0)" ::: "memory");
    __builtin_amdgcn_s_barrier();
    if (t + 2 < NCH) stage(t + 2);
    const char* base = lds + (t % 3) * CH_STRIDE + hi * 512 + lo5 * 16;
    const int g = t - NCHA;
    f32x16 accV = zero16;
    __builtin_amdgcn_s_setprio(1);
#pragma unroll
    for (int ks = 0; ks < NKS; ++ks) {
      bf16x8 vb = *(const bf16x8*)(base + ks * 1024);
      accV = __builtin_amdgcn_mfma_f32_32x32x16_bf16(a[ks], vb, accV, 0, 0, 0);
    }
    __builtin_amdgcn_s_setprio(0);
    int h = g * 32 + lo5;
#pragma unroll
    for (int tt = 0; tt < 8; ++tt) {
      int w = wid * 16 + (tt >> 1) * 4 + (tt & 1) + hi * 2;
      long gw = (long)(blockIdx.x * WPB + w);
      float v0 = accV[2 * tt], v1 = accV[2 * tt + 1];
      out[gw * 1024 + h]       = at[tt][0] * v0 + at[tt][1] * v1;
      out[gw * 1024 + 512 + h] = at[tt][2] * v0 + at[tt][3] * v1;
    }
  }
}

extern "C" void kernel_launch(void* const* d_in, const int* in_sizes, int n_in,
                              void* d_out, int out_size, void* d_ws, size_t ws_size,
                              hipStream_t stream) {
  const float* charv = (const float*)d_in[0];
  const float* wordv = (const float*)d_in[1];
  const float* Wk = (const float*)d_in[2];
  const float* bk = (const float*)d_in[3];
  const float* Wq = (const float*)d_in[4];
  const float* bq = (const float*)d_in[5];
  const float* Wv = (const float*)d_in[6];
  const float* bv = (const float*)d_in[7];
  float* out = (float*)d_out;
  unsigned short* wt = (unsigned short*)d_ws;  // 26*10240*2 = 532,480 B

  prep_weights<<<(NCH * 9728 + 255) / 256, 256, 0, stream>>>(
      Wq, Wk, Wv, bq, bk, bv, wt);

  const int lds_bytes = 3 * CH_STRIDE + 256 * 4;  // 62,464 B -> 2 blocks/CU
  fused_attn<<<65536 / ROWS, 256, lds_bytes, stream>>>(charv, wordv, wt, out);
}

// Round 18
// 98.920 us; speedup vs baseline: 1.1357x; 1.0736x over previous
//
#include <hip/hip_runtime.h>

#define D 300
#define HDIM 512
#define ROWS 128          // X rows per block (grid 512)
#define WPB 64            // words per block
#define NKS 19            // k-extent 304 = 19*16 (300 data + bias@300 + pad)
#define NCHA 5            // Mt chunks (64 cols each, 320 cols)
#define NCH 13            // 5 Mt + 8 V chunks
#define CH_STRIDE 40960   // chunk stride bytes (2*19456 used + 2KB pad)
#define CH_SELEMS 20480
#define REGB 19456        // 32-col region bytes (304 k * 32 * 2)
#define SEGW 10           // 1KB staging segments per wave per chunk (40/4)

typedef __attribute__((ext_vector_type(16))) float f32x16;
typedef __attribute__((ext_vector_type(4))) float f32x4;
typedef __attribute__((ext_vector_type(8))) short bf16x8;

__device__ inline unsigned short f2bf(float f) {
  unsigned int u = __float_as_uint(f);
  unsigned int r = (u + 0x7fffu + ((u >> 16) & 1u)) >> 16;
  return (unsigned short)r;
}

__device__ inline void gload_lds16(const void* g, void* l) {
  __builtin_amdgcn_global_load_lds(
      (const __attribute__((address_space(1))) unsigned int*)g,
      (__attribute__((address_space(3))) unsigned int*)l, 16, 0, 0);
}

// ---- Stage 1: Mt = W~q * W~k^T (320x320 f32, zero-padded past 301) via
// LDS-tiled GEMM. Replaces R15-R17's naive per-element dot (400 MB L2 reads,
// ~14 us) with ~13 MB (~2 us). qa/kb padded [32][133]: (133*col+kk)%32 =
// (5*col+kk)%32 -> conflict-free.
__global__ __launch_bounds__(256) void compute_mt(
    const float* __restrict__ Wq, const float* __restrict__ Wk,
    const float* __restrict__ bq, const float* __restrict__ bk,
    float* __restrict__ mtf) {
  __shared__ float qa[32][133];
  __shared__ float kb[32][133];
  const int bi = blockIdx.x / 10, bj = blockIdx.x % 10;
  const int tid = threadIdx.x;
  const int col = tid & 31, rg = tid >> 5;  // rg 0..7
  float acc[4] = {0.f, 0.f, 0.f, 0.f};
  for (int kc = 0; kc < 4; ++kc) {
    __syncthreads();
#pragma unroll
    for (int q = 0; q < 4; ++q) {
      int lin = tid + q * 256;              // 0..1023
      int row = lin >> 5, c4 = (lin & 31) * 4;
      int gq = bi * 32 + row, gk = bj * 32 + row;
      float4 vq = {0.f, 0.f, 0.f, 0.f}, vk = {0.f, 0.f, 0.f, 0.f};
      if (gq < 300)       vq = *(const float4*)(Wq + gq * HDIM + kc * 128 + c4);
      else if (gq == 300) vq = *(const float4*)(bq + kc * 128 + c4);
      if (gk < 300)       vk = *(const float4*)(Wk + gk * HDIM + kc * 128 + c4);
      else if (gk == 300) vk = *(const float4*)(bk + kc * 128 + c4);
      *(float4*)&qa[row][c4] = vq;
      *(float4*)&kb[row][c4] = vk;
    }
    __syncthreads();
    for (int kk = 0; kk < 128; ++kk) {
      float kv = kb[col][kk];
#pragma unroll
      for (int s = 0; s < 4; ++s) acc[s] += qa[rg + 8 * s][kk] * kv;
    }
  }
#pragma unroll
  for (int s = 0; s < 4; ++s)
    mtf[(bi * 32 + rg + 8 * s) * 320 + bj * 32 + col] = acc[s];
}

// ---- Stage 2: pack into chunks. Chunks 0-4: Mt cols c*64.. (2 regions of
// 32); 5-12: W~v (bias@k=300). Region layout [ks19][kh2][col32][e8]
// (R10-verified conflict-free). Writes linear/coalesced.
__global__ __launch_bounds__(256) void prep_weights(
    const float* __restrict__ Wv, const float* __restrict__ bv,
    const float* __restrict__ mtf, unsigned short* __restrict__ wt) {
  int idx = blockIdx.x * 256 + threadIdx.x;
  if (idx >= NCH * CH_SELEMS) return;
  int c = idx / CH_SELEMS, r = idx - c * CH_SELEMS;
  float v = 0.0f;
  if (r < 2 * 9728) {
    int reg = r / 9728, r2 = r - reg * 9728;
    int ks = r2 >> 9, r3 = r2 & 511;
    int kh = r3 >> 8, r4 = r3 & 255;
    int col = r4 >> 3, e = r4 & 7;
    int k1 = ks * 16 + kh * 8 + e;          // <= 303
    if (c < NCHA) {
      int k2 = c * 64 + reg * 32 + col;     // <= 319
      v = mtf[k1 * 320 + k2];               // rows 301-319 are zero
    } else {
      int gcol = (c - NCHA) * 64 + reg * 32 + col;
      if (k1 < D)       v = Wv[k1 * HDIM + gcol];
      else if (k1 == D) v = bv[gcol];
    }
  }
  wt[idx] = f2bf(v);
}

// ---- Fused: 13 phases (phase-count hypothesis: R14 24ph ~= R17 26ph ~=
// 3.5us/phase regardless of work; R15 ran 13ph but spilled). 256 threads so
// the ~150-reg live set fits (R17: 192 regs clean; 512-thr caps at 128 ->
// R15's 120 MB scratch). Lane-local softmax: after the xor-reduce each lane
// holds its 8 words' full 2x2 scores -> no LDS/barriers for softmax.
__global__ __launch_bounds__(256) void fused_attn(
    const float* __restrict__ charv, const float* __restrict__ wordv,
    const unsigned short* __restrict__ wt, float* __restrict__ out) {
  extern __shared__ char lds[];

  const int tid  = threadIdx.x;
  const int wid  = tid >> 6;    // 0..3, wave rows wid*32..+32
  const int lane = tid & 63;
  const int lo5  = lane & 31;
  const int hi   = lane >> 5;

  auto stage = [&](int t) {
    const char* src = (const char*)wt + (long)t * CH_STRIDE + wid * (SEGW * 1024) + lane * 16;
    char* dst = lds + (t % 3) * CH_STRIDE + wid * (SEGW * 1024);
#pragma unroll
    for (int j = 0; j < SEGW; ++j)
      gload_lds16(src + j * 1024, dst + j * 1024);
  };

  stage(0);
  stage(1);

  // A-frag: lane holds x~[row=lo5][k=ks*16+hi*8+e]; ones-feature at k=300.
  bf16x8 a[NKS];
  {
    int row = blockIdx.x * ROWS + wid * 32 + lo5;
    const float* rp = ((row & 1) ? charv : wordv) + (row >> 1) * D;
#pragma unroll
    for (int ks = 0; ks < NKS; ++ks) {
      int k0 = ks * 16 + hi * 8;
      float4 lo = {0.f, 0.f, 0.f, 0.f}, hif = {0.f, 0.f, 0.f, 0.f};
      if (k0 + 8 <= D) {
        lo  = *(const float4*)(rp + k0);
        hif = *(const float4*)(rp + k0 + 4);
      } else if (k0 < D) {
        lo  = *(const float4*)(rp + k0);
      }
      bf16x8 v;
      v[0] = (short)f2bf(lo.x);  v[1] = (short)f2bf(lo.y);
      v[2] = (short)f2bf(lo.z);  v[3] = (short)f2bf(lo.w);
      v[4] = (short)f2bf(hif.x); v[5] = (short)f2bf(hif.y);
      v[6] = (short)f2bf(hif.z); v[7] = (short)f2bf(hif.w);
      if (ks == 18 && hi == 1) v[4] = (short)0x3F80;  // bf16(1.0) at k=300
      a[ks] = v;
    }
  }

  // Identity B-frags (lane-constant): i0 cols 0-15, i1 cols 16-31.
  bf16x8 i0, i1;
#pragma unroll
  for (int e = 0; e < 8; ++e) {
    i0[e] = (lo5 == hi * 8 + e)      ? (short)0x3F80 : (short)0;
    i1[e] = (lo5 == 16 + hi * 8 + e) ? (short)0x3F80 : (short)0;
  }

  float p[32];
#pragma unroll
  for (int t = 0; t < 32; ++t) p[t] = 0.f;

  const f32x16 zero16 = {0.f, 0.f, 0.f, 0.f, 0.f, 0.f, 0.f, 0.f,
                         0.f, 0.f, 0.f, 0.f, 0.f, 0.f, 0.f, 0.f};

  // ---- Phase A: 5 Mt chunks (unrolled: a[ks0] must be static, rule #20)
#pragma unroll
  for (int t = 0; t < NCHA; ++t) {
    asm volatile("s_waitcnt vmcnt(10)" ::: "memory");  // own stage(t) landed
    asm volatile("s_waitcnt lgkmcnt(0)" ::: "memory");
    __builtin_amdgcn_s_barrier();
    stage(t + 2);
    const char* cb = lds + (t % 3) * CH_STRIDE;
#pragma unroll
    for (int r = 0; r < 2; ++r) {
      const char* base = cb + r * REGB + hi * 512 + lo5 * 16;
      f32x16 accY = zero16;
      __builtin_amdgcn_s_setprio(1);
#pragma unroll
      for (int ks = 0; ks < NKS; ++ks) {
        bf16x8 mb = *(const bf16x8*)(base + ks * 1024);
        accY = __builtin_amdgcn_mfma_f32_32x32x16_bf16(a[ks], mb, accY, 0, 0, 0);
      }
      // x~^T via identity MFMAs: accX[r'] = x~[crow(r')][t*64+r*32+lo5]
      const int ks0 = t * 4 + r * 2;
      f32x16 accX = __builtin_amdgcn_mfma_f32_32x32x16_bf16(a[ks0], i0, zero16, 0, 0, 0);
      if (ks0 + 1 < NKS)
        accX = __builtin_amdgcn_mfma_f32_32x32x16_bf16(a[ks0 + 1], i1, accX, 0, 0, 0);
      __builtin_amdgcn_s_setprio(0);
#pragma unroll
      for (int tt = 0; tt < 8; ++tt)
#pragma unroll
        for (int i = 0; i < 2; ++i)
#pragma unroll
          for (int j = 0; j < 2; ++j)
            p[tt * 4 + i * 2 + j] += accY[2 * tt + i] * accX[2 * tt + j];
    }
  }

  // ---- reduce over 32 col-lanes; softmax fully lane-local (no LDS/barrier)
#pragma unroll
  for (int t = 0; t < 32; ++t) {
    float v = p[t];
    v += __shfl_xor(v, 1);
    v += __shfl_xor(v, 2);
    v += __shfl_xor(v, 4);
    v += __shfl_xor(v, 8);
    v += __shfl_xor(v, 16);
    p[t] = v;
  }
  f32x4 at[8];
  {
    const float sc = 0.044194173824159216f;  // 1/sqrt(512)
#pragma unroll
    for (int tt = 0; tt < 8; ++tt) {
      float s0 = p[tt * 4 + 0] * sc, s1 = p[tt * 4 + 1] * sc;
      float s2 = p[tt * 4 + 2] * sc, s3 = p[tt * 4 + 3] * sc;
      float m0 = fmaxf(s0, s1), m1 = fmaxf(s2, s3);
      float e00 = expf(s0 - m0), e01 = expf(s1 - m0);
      float e10 = expf(s2 - m1), e11 = expf(s3 - m1);
      float v0 = 1.0f / (e00 + e01), v1 = 1.0f / (e10 + e11);
      at[tt] = (f32x4){e00 * v0, e01 * v0, e10 * v1, e11 * v1};
    }
  }

  // ---- Phase B: 8 V chunks; vmcnt(42) = 10 stage + 32 stores newer
  for (int t = NCHA; t < NCH; ++t) {
    if (t == NCHA) asm volatile("s_waitcnt vmcnt(10)" ::: "memory");
    else           asm volatile("s_waitcnt vmcnt(42)" ::: "memory");
    asm volatile("s_waitcnt lgkmcnt(0)" ::: "memory");
    __builtin_amdgcn_s_barrier();
    if (t + 2 < NCH) stage(t + 2);
    const char* cb = lds + (t % 3) * CH_STRIDE;
    const int g = t - NCHA;
#pragma unroll
    for (int ct = 0; ct < 2; ++ct) {
      const char* base = cb + ct * REGB + hi * 512 + lo5 * 16;
      f32x16 accV = zero16;
      __builtin_amdgcn_s_setprio(1);
#pragma unroll
      for (int ks = 0; ks < NKS; ++ks) {
        bf16x8 vb = *(const bf16x8*)(base + ks * 1024);
        accV = __builtin_amdgcn_mfma_f32_32x32x16_bf16(a[ks], vb, accV, 0, 0, 0);
      }
      __builtin_amdgcn_s_setprio(0);
      int h = g * 64 + ct * 32 + lo5;
#pragma unroll
      for (int tt = 0; tt < 8; ++tt) {
        int w = wid * 16 + (tt >> 1) * 4 + (tt & 1) + hi * 2;
        long gw = (long)(blockIdx.x * WPB + w);
        float v0 = accV[2 * tt], v1 = accV[2 * tt + 1];
        out[gw * 1024 + h]       = at[tt][0] * v0 + at[tt][1] * v1;
        out[gw * 1024 + 512 + h] = at[tt][2] * v0 + at[tt][3] * v1;
      }
    }
  }
}

extern "C" void kernel_launch(void* const* d_in, const int* in_sizes, int n_in,
                              void* d_out, int out_size, void* d_ws, size_t ws_size,
                              hipStream_t stream) {
  const float* charv = (const float*)d_in[0];
  const float* wordv = (const float*)d_in[1];
  const float* Wk = (const float*)d_in[2];
  const float* bk = (const float*)d_in[3];
  const float* Wq = (const float*)d_in[4];
  const float* bq = (const float*)d_in[5];
  const float* Wv = (const float*)d_in[6];
  const float* bv = (const float*)d_in[7];
  float* out = (float*)d_out;
  unsigned short* wt = (unsigned short*)d_ws;            // 13*20480*2 = 532,480 B
  float* mtf = (float*)((char*)d_ws + NCH * CH_SELEMS * 2);  // 320*320*4 = 409,600 B

  compute_mt<<<100, 256, 0, stream>>>(Wq, Wk, bq, bk, mtf);
  prep_weights<<<(NCH * CH_SELEMS + 255) / 256, 256, 0, stream>>>(Wv, bv, mtf, wt);

  const int lds_bytes = 3 * CH_STRIDE;  // 122,880 B
  fused_attn<<<65536 / ROWS, 256, lds_bytes, stream>>>(charv, wordv, wt, out);
}